// Round 1
// baseline (972.890 us; speedup 1.0000x reference)
//
#include <hip/hip_runtime.h>

#define N_NODES 100000
#define E_EDGES 3200000
#define F_IN 11
#define F_H 64
#define F_E 32

// ws layout (floats):
//   deg  : [0, N)
//   agg1 : [N*1, N*12)    (N x 11)
//   agg2 : [N*12, N*44)   (N x 32)
//   h    : [N*44, N*108)  (N x 64)
//   p2   : [N*108, N*140) (N x 32)
// total N*140 floats = 56 MB

// ---- edge kernel 1: scatter x[src] -> agg1[dst], and degree count ----
// 16 lanes per edge: lanes 0..10 = features, lane 11 = degree, 12..15 idle
__global__ void edge_agg1_kernel(const int* __restrict__ src,
                                 const int* __restrict__ dst,
                                 const float* __restrict__ x,
                                 float* __restrict__ agg1,
                                 float* __restrict__ deg) {
    long long tid = (long long)blockIdx.x * blockDim.x + threadIdx.x;
    int e = (int)(tid >> 4);
    int f = (int)(tid & 15);
    if (e >= E_EDGES) return;
    int d = dst[e];
    if (f < F_IN) {
        int s = src[e];
        atomicAdd(&agg1[(long long)d * F_IN + f], x[(long long)s * F_IN + f]);
    } else if (f == F_IN) {
        atomicAdd(&deg[d], 1.0f);
    }
}

// ---- node kernel: h = relu(agg1/deg * W1l + x * W1r + b1), thread = (n, j<64)
__global__ void layer1_node_kernel(const float* __restrict__ x,
                                   const float* __restrict__ agg1,
                                   const float* __restrict__ deg,
                                   const float* __restrict__ W1l,
                                   const float* __restrict__ W1r,
                                   const float* __restrict__ b1,
                                   float* __restrict__ h) {
    long long tid = (long long)blockIdx.x * blockDim.x + threadIdx.x;
    int n = (int)(tid >> 6);
    int j = (int)(tid & 63);
    if (n >= N_NODES) return;
    float invd = 1.0f / fmaxf(deg[n], 1.0f);
    float acc = b1[j];
    #pragma unroll
    for (int f = 0; f < F_IN; ++f) {
        float a = agg1[(long long)n * F_IN + f] * invd;
        float xv = x[(long long)n * F_IN + f];
        acc += a * W1l[f * F_H + j] + xv * W1r[f * F_H + j];
    }
    h[(long long)n * F_H + j] = fmaxf(acc, 0.0f);
}

// ---- node kernel: p2 = h * W2l, thread = (n, j<32)
__global__ void p2_kernel(const float* __restrict__ h,
                          const float* __restrict__ W2l,
                          float* __restrict__ p2) {
    long long tid = (long long)blockIdx.x * blockDim.x + threadIdx.x;
    int n = (int)(tid >> 5);
    int j = (int)(tid & 31);
    if (n >= N_NODES) return;
    float acc = 0.0f;
    const float* hrow = h + (long long)n * F_H;
    #pragma unroll
    for (int k = 0; k < F_H; ++k) {
        acc += hrow[k] * W2l[k * F_E + j];
    }
    p2[(long long)n * F_E + j] = acc;
}

// ---- edge kernel 2: scatter p2[src] -> agg2[dst], 32 lanes per edge
__global__ void edge_agg2_kernel(const int* __restrict__ src,
                                 const int* __restrict__ dst,
                                 const float* __restrict__ p2,
                                 float* __restrict__ agg2) {
    long long tid = (long long)blockIdx.x * blockDim.x + threadIdx.x;
    int e = (int)(tid >> 5);
    int f = (int)(tid & 31);
    if (e >= E_EDGES) return;
    int s = src[e];
    int d = dst[e];
    atomicAdd(&agg2[(long long)d * F_E + f], p2[(long long)s * F_E + f]);
}

// ---- node kernel: emb = relu(agg2/deg + h * W2r + b2), thread = (n, j<32)
__global__ void layer2_node_kernel(const float* __restrict__ h,
                                   const float* __restrict__ agg2,
                                   const float* __restrict__ deg,
                                   const float* __restrict__ W2r,
                                   const float* __restrict__ b2,
                                   float* __restrict__ emb_out) {
    long long tid = (long long)blockIdx.x * blockDim.x + threadIdx.x;
    int n = (int)(tid >> 5);
    int j = (int)(tid & 31);
    if (n >= N_NODES) return;
    float invd = 1.0f / fmaxf(deg[n], 1.0f);
    float acc = b2[j] + agg2[(long long)n * F_E + j] * invd;
    const float* hrow = h + (long long)n * F_H;
    #pragma unroll
    for (int k = 0; k < F_H; ++k) {
        acc += hrow[k] * W2r[k * F_E + j];
    }
    emb_out[(long long)n * F_E + j] = fmaxf(acc, 0.0f);
}

// ---- node kernel: logits = emb * Wc + bc, thread = n
__global__ void logits_kernel(const float* __restrict__ emb,
                              const float* __restrict__ Wc,
                              const float* __restrict__ bc,
                              float* __restrict__ logits) {
    long long tid = (long long)blockIdx.x * blockDim.x + threadIdx.x;
    int n = (int)tid;
    if (n >= N_NODES) return;
    float a0 = bc[0], a1 = bc[1], a2 = bc[2];
    const float* erow = emb + (long long)n * F_E;
    #pragma unroll
    for (int k = 0; k < F_E; ++k) {
        float e = erow[k];
        a0 += e * Wc[k * 3 + 0];
        a1 += e * Wc[k * 3 + 1];
        a2 += e * Wc[k * 3 + 2];
    }
    logits[(long long)n * 3 + 0] = a0;
    logits[(long long)n * 3 + 1] = a1;
    logits[(long long)n * 3 + 2] = a2;
}

extern "C" void kernel_launch(void* const* d_in, const int* in_sizes, int n_in,
                              void* d_out, int out_size, void* d_ws, size_t ws_size,
                              hipStream_t stream) {
    const float* x   = (const float*)d_in[0];
    const int*   ei  = (const int*)d_in[1];
    const float* W1l = (const float*)d_in[2];
    const float* W1r = (const float*)d_in[3];
    const float* b1  = (const float*)d_in[4];
    const float* W2l = (const float*)d_in[5];
    const float* W2r = (const float*)d_in[6];
    const float* b2  = (const float*)d_in[7];
    const float* Wc  = (const float*)d_in[8];
    const float* bc  = (const float*)d_in[9];

    const int* src = ei;             // edge_index[0]
    const int* dst = ei + E_EDGES;   // edge_index[1]

    float* out    = (float*)d_out;
    float* logits = out;                       // [N, 3]
    float* emb    = out + (size_t)N_NODES * 3; // [N, 32]

    float* ws   = (float*)d_ws;
    float* deg  = ws;
    float* agg1 = ws + (size_t)N_NODES;
    float* agg2 = ws + (size_t)N_NODES * 12;
    float* h    = ws + (size_t)N_NODES * 44;
    float* p2   = ws + (size_t)N_NODES * 108;

    // zero deg + agg1 + agg2 (first N*44 floats)
    hipMemsetAsync(d_ws, 0, (size_t)N_NODES * 44 * sizeof(float), stream);

    const int BS = 256;

    // edge agg layer 1: E*16 threads
    {
        long long total = (long long)E_EDGES * 16;
        int blocks = (int)((total + BS - 1) / BS);
        edge_agg1_kernel<<<blocks, BS, 0, stream>>>(src, dst, x, agg1, deg);
    }
    // layer 1 node: N*64 threads
    {
        long long total = (long long)N_NODES * F_H;
        int blocks = (int)((total + BS - 1) / BS);
        layer1_node_kernel<<<blocks, BS, 0, stream>>>(x, agg1, deg, W1l, W1r, b1, h);
    }
    // p2 = h @ W2l: N*32 threads
    {
        long long total = (long long)N_NODES * F_E;
        int blocks = (int)((total + BS - 1) / BS);
        p2_kernel<<<blocks, BS, 0, stream>>>(h, W2l, p2);
    }
    // edge agg layer 2: E*32 threads
    {
        long long total = (long long)E_EDGES * F_E;
        int blocks = (int)((total + BS - 1) / BS);
        edge_agg2_kernel<<<blocks, BS, 0, stream>>>(src, dst, p2, agg2);
    }
    // layer 2 node: N*32 threads
    {
        long long total = (long long)N_NODES * F_E;
        int blocks = (int)((total + BS - 1) / BS);
        layer2_node_kernel<<<blocks, BS, 0, stream>>>(h, agg2, deg, W2r, b2, emb);
    }
    // logits: N threads
    {
        long long total = (long long)N_NODES;
        int blocks = (int)((total + BS - 1) / BS);
        logits_kernel<<<blocks, BS, 0, stream>>>(emb, Wc, bc, logits);
    }
}

// Round 2
// 693.670 us; speedup vs baseline: 1.4025x; 1.4025x over previous
//
#include <hip/hip_runtime.h>

#define N_NODES 100000
#define E_EDGES 3200000
#define F_IN 11
#define F_H 64
#define F_E 32

#define SCAN_CHUNK 1024  // elements per scan block (256 threads x 4)
#define SCAN_NB ((N_NODES + SCAN_CHUNK - 1) / SCAN_CHUNK)  // 98

// ---------------- CSR construction ----------------

// histogram: deg_i[dst[e]] += 1
__global__ void hist_kernel(const int* __restrict__ dst, int* __restrict__ deg_i) {
    int e = blockIdx.x * blockDim.x + threadIdx.x;
    if (e >= E_EDGES) return;
    atomicAdd(&deg_i[dst[e]], 1);
}

// scan stage 1: per-block (1024-element chunk) sums
__global__ void scan_partial_kernel(const int* __restrict__ deg_i, int* __restrict__ partials) {
    __shared__ int lds[256];
    int base = blockIdx.x * SCAN_CHUNK + threadIdx.x * 4;
    int s = 0;
    #pragma unroll
    for (int k = 0; k < 4; ++k) {
        int idx = base + k;
        if (idx < N_NODES) s += deg_i[idx];
    }
    lds[threadIdx.x] = s;
    __syncthreads();
    for (int off = 128; off > 0; off >>= 1) {
        if (threadIdx.x < off) lds[threadIdx.x] += lds[threadIdx.x + off];
        __syncthreads();
    }
    if (threadIdx.x == 0) partials[blockIdx.x] = lds[0];
}

// scan stage 2: exclusive scan of partials (SCAN_NB <= 256), single block of 256
__global__ void scan_top_kernel(int* __restrict__ partials) {
    __shared__ int lds[256];
    int t = threadIdx.x;
    int v = (t < SCAN_NB) ? partials[t] : 0;
    lds[t] = v;
    __syncthreads();
    int incl = v;
    for (int off = 1; off < 256; off <<= 1) {
        int tmp = (t >= off) ? lds[t - off] : 0;
        __syncthreads();
        incl += tmp;
        lds[t] = incl;
        __syncthreads();
    }
    if (t < SCAN_NB) partials[t] = incl - v;  // exclusive
}

// scan stage 3: recompute local scan, add block offset, write offsets + cursor
__global__ void scan_apply_kernel(const int* __restrict__ deg_i,
                                  const int* __restrict__ partials,
                                  int* __restrict__ offsets,
                                  int* __restrict__ cursor) {
    __shared__ int lds[256];
    int b = blockIdx.x, t = threadIdx.x;
    int base = b * SCAN_CHUNK + t * 4;
    int v[4];
    int s = 0;
    #pragma unroll
    for (int k = 0; k < 4; ++k) {
        int idx = base + k;
        v[k] = (idx < N_NODES) ? deg_i[idx] : 0;
        s += v[k];
    }
    lds[t] = s;
    __syncthreads();
    int incl = s;
    for (int off = 1; off < 256; off <<= 1) {
        int tmp = (t >= off) ? lds[t - off] : 0;
        __syncthreads();
        incl += tmp;
        lds[t] = incl;
        __syncthreads();
    }
    int run = incl - s + partials[b];  // exclusive start for this thread's 4 elements
    #pragma unroll
    for (int k = 0; k < 4; ++k) {
        int idx = base + k;
        if (idx < N_NODES) {
            offsets[idx] = run;
            cursor[idx] = run;
            run += v[k];
        }
    }
}

// fill: csr_src[cursor[dst[e]]++] = src[e]
__global__ void fill_kernel(const int* __restrict__ src,
                            const int* __restrict__ dst,
                            int* __restrict__ cursor,
                            int* __restrict__ csr_src) {
    int e = blockIdx.x * blockDim.x + threadIdx.x;
    if (e >= E_EDGES) return;
    int d = dst[e];
    int pos = atomicAdd(&cursor[d], 1);
    csr_src[pos] = src[e];
}

// ---------------- layer 1 ----------------

// gather agg1[n][f] = sum_{s in nbr(n)} x[s][f]; 16 lanes/node (f<11 active)
__global__ void gather1_kernel(const int* __restrict__ csr_src,
                               const int* __restrict__ offsets,
                               const int* __restrict__ deg_i,
                               const float* __restrict__ x,
                               float* __restrict__ agg1) {
    int tid = blockIdx.x * blockDim.x + threadIdx.x;
    int n = tid >> 4;
    int f = tid & 15;
    if (n >= N_NODES || f >= F_IN) return;
    int start = offsets[n];
    int end = start + deg_i[n];
    float a0 = 0.f, a1 = 0.f, a2 = 0.f, a3 = 0.f;
    int i = start;
    for (; i + 4 <= end; i += 4) {
        int s0 = csr_src[i], s1 = csr_src[i + 1], s2 = csr_src[i + 2], s3 = csr_src[i + 3];
        a0 += x[s0 * F_IN + f];
        a1 += x[s1 * F_IN + f];
        a2 += x[s2 * F_IN + f];
        a3 += x[s3 * F_IN + f];
    }
    for (; i < end; ++i) a0 += x[csr_src[i] * F_IN + f];
    agg1[n * F_IN + f] = a0 + a1 + a2 + a3;
}

// h = relu(agg1/deg * W1l + x * W1r + b1), thread = (n, j<64)
__global__ void layer1_node_kernel(const float* __restrict__ x,
                                   const float* __restrict__ agg1,
                                   const int* __restrict__ deg_i,
                                   const float* __restrict__ W1l,
                                   const float* __restrict__ W1r,
                                   const float* __restrict__ b1,
                                   float* __restrict__ h) {
    int tid = blockIdx.x * blockDim.x + threadIdx.x;
    int n = tid >> 6;
    int j = tid & 63;
    if (n >= N_NODES) return;
    float invd = 1.0f / fmaxf((float)deg_i[n], 1.0f);
    float acc = b1[j];
    #pragma unroll
    for (int f = 0; f < F_IN; ++f) {
        float a = agg1[n * F_IN + f] * invd;
        float xv = x[n * F_IN + f];
        acc += a * W1l[f * F_H + j] + xv * W1r[f * F_H + j];
    }
    h[n * F_H + j] = fmaxf(acc, 0.0f);
}

// p2 = h @ W2l, thread = (n, j<32)
__global__ void p2_kernel(const float* __restrict__ h,
                          const float* __restrict__ W2l,
                          float* __restrict__ p2) {
    int tid = blockIdx.x * blockDim.x + threadIdx.x;
    int n = tid >> 5;
    int j = tid & 31;
    if (n >= N_NODES) return;
    float acc = 0.0f;
    const float* hrow = h + n * F_H;
    #pragma unroll
    for (int k = 0; k < F_H; ++k) acc += hrow[k] * W2l[k * F_E + j];
    p2[n * F_E + j] = acc;
}

// ---------------- layer 2 fused: gather p2 + h@W2r + relu + logits ----------------
// 32 lanes per node (j = feature). Logits via intra-32-lane shuffle reduction.
__global__ void layer2_fused_kernel(const int* __restrict__ csr_src,
                                    const int* __restrict__ offsets,
                                    const int* __restrict__ deg_i,
                                    const float* __restrict__ p2,
                                    const float* __restrict__ h,
                                    const float* __restrict__ W2r,
                                    const float* __restrict__ b2,
                                    const float* __restrict__ Wc,
                                    const float* __restrict__ bc,
                                    float* __restrict__ emb,
                                    float* __restrict__ logits) {
    int tid = blockIdx.x * blockDim.x + threadIdx.x;
    int n = tid >> 5;
    int j = tid & 31;
    if (n >= N_NODES) return;
    int start = offsets[n];
    int cnt = deg_i[n];
    int end = start + cnt;
    float a0 = 0.f, a1 = 0.f, a2 = 0.f, a3 = 0.f;
    int i = start;
    for (; i + 4 <= end; i += 4) {
        int s0 = csr_src[i], s1 = csr_src[i + 1], s2 = csr_src[i + 2], s3 = csr_src[i + 3];
        a0 += p2[s0 * F_E + j];
        a1 += p2[s1 * F_E + j];
        a2 += p2[s2 * F_E + j];
        a3 += p2[s3 * F_E + j];
    }
    for (; i < end; ++i) a0 += p2[csr_src[i] * F_E + j];
    float invd = 1.0f / fmaxf((float)cnt, 1.0f);
    float acc = (a0 + a1 + a2 + a3) * invd + b2[j];
    const float* hrow = h + n * F_H;
    #pragma unroll
    for (int k = 0; k < F_H; ++k) acc += hrow[k] * W2r[k * F_E + j];
    float e = fmaxf(acc, 0.0f);
    emb[n * F_E + j] = e;
    // logits: 3 dot-products over the 32 lanes of this node
    float c0 = e * Wc[j * 3 + 0];
    float c1 = e * Wc[j * 3 + 1];
    float c2 = e * Wc[j * 3 + 2];
    #pragma unroll
    for (int m = 1; m < 32; m <<= 1) {
        c0 += __shfl_xor(c0, m);
        c1 += __shfl_xor(c1, m);
        c2 += __shfl_xor(c2, m);
    }
    if (j == 0) {
        logits[n * 3 + 0] = c0 + bc[0];
        logits[n * 3 + 1] = c1 + bc[1];
        logits[n * 3 + 2] = c2 + bc[2];
    }
}

extern "C" void kernel_launch(void* const* d_in, const int* in_sizes, int n_in,
                              void* d_out, int out_size, void* d_ws, size_t ws_size,
                              hipStream_t stream) {
    const float* x   = (const float*)d_in[0];
    const int*   ei  = (const int*)d_in[1];
    const float* W1l = (const float*)d_in[2];
    const float* W1r = (const float*)d_in[3];
    const float* b1  = (const float*)d_in[4];
    const float* W2l = (const float*)d_in[5];
    const float* W2r = (const float*)d_in[6];
    const float* b2  = (const float*)d_in[7];
    const float* Wc  = (const float*)d_in[8];
    const float* bc  = (const float*)d_in[9];

    const int* src = ei;            // edge_index[0]
    const int* dst = ei + E_EDGES;  // edge_index[1]

    float* out    = (float*)d_out;
    float* logits = out;                       // [N, 3]
    float* emb    = out + (size_t)N_NODES * 3; // [N, 32]

    // ws layout: ints first, then floats
    int* ws_i     = (int*)d_ws;
    int* deg_i    = ws_i;                    // N
    int* offsets  = ws_i + N_NODES;          // N
    int* cursor   = ws_i + 2 * N_NODES;      // N
    int* partials = ws_i + 3 * N_NODES;      // 256
    int* csr_src  = ws_i + 3 * N_NODES + 256;// E
    float* fbase  = (float*)(csr_src + E_EDGES);
    float* h      = fbase;                        // 64N
    float* agg1   = fbase + (size_t)64 * N_NODES; // 11N
    float* p2     = fbase + (size_t)64 * N_NODES; // 32N (reuses agg1 region after layer1)

    // zero only the histogram
    hipMemsetAsync(deg_i, 0, (size_t)N_NODES * sizeof(int), stream);

    const int BS = 256;
    int eblocks = (E_EDGES + BS - 1) / BS;

    hist_kernel<<<eblocks, BS, 0, stream>>>(dst, deg_i);
    scan_partial_kernel<<<SCAN_NB, BS, 0, stream>>>(deg_i, partials);
    scan_top_kernel<<<1, 256, 0, stream>>>(partials);
    scan_apply_kernel<<<SCAN_NB, BS, 0, stream>>>(deg_i, partials, offsets, cursor);
    fill_kernel<<<eblocks, BS, 0, stream>>>(src, dst, cursor, csr_src);

    gather1_kernel<<<(N_NODES * 16 + BS - 1) / BS, BS, 0, stream>>>(csr_src, offsets, deg_i, x, agg1);
    layer1_node_kernel<<<(N_NODES * 64 + BS - 1) / BS, BS, 0, stream>>>(x, agg1, deg_i, W1l, W1r, b1, h);
    p2_kernel<<<(N_NODES * 32 + BS - 1) / BS, BS, 0, stream>>>(h, W2l, p2);
    layer2_fused_kernel<<<(N_NODES * 32 + BS - 1) / BS, BS, 0, stream>>>(
        csr_src, offsets, deg_i, p2, h, W2r, b2, Wc, bc, emb, logits);
}

// Round 3
// 543.403 us; speedup vs baseline: 1.7904x; 1.2765x over previous
//
#include <hip/hip_runtime.h>

#define N_NODES 100000
#define E_EDGES 3200000
#define F_IN 11
#define F_H 64
#define F_E 32

#define SCAN_CHUNK 1024
#define SCAN_NB ((N_NODES + SCAN_CHUNK - 1) / SCAN_CHUNK)  // 98

#define BUCKETS ((N_NODES + 255) >> 8)   // 391 coarse buckets (dst>>8)
#define CHUNK_A 4096
#define NWG_A ((E_EDGES + CHUNK_A - 1) / CHUNK_A)  // 782

// ---------------- CSR construction ----------------

__global__ void hist_kernel(const int* __restrict__ dst, int* __restrict__ deg_i) {
    int e = blockIdx.x * blockDim.x + threadIdx.x;
    if (e >= E_EDGES) return;
    atomicAdd(&deg_i[dst[e]], 1);
}

__global__ void scan_partial_kernel(const int* __restrict__ deg_i, int* __restrict__ partials) {
    __shared__ int lds[256];
    int base = blockIdx.x * SCAN_CHUNK + threadIdx.x * 4;
    int s = 0;
    #pragma unroll
    for (int k = 0; k < 4; ++k) {
        int idx = base + k;
        if (idx < N_NODES) s += deg_i[idx];
    }
    lds[threadIdx.x] = s;
    __syncthreads();
    for (int off = 128; off > 0; off >>= 1) {
        if (threadIdx.x < off) lds[threadIdx.x] += lds[threadIdx.x + off];
        __syncthreads();
    }
    if (threadIdx.x == 0) partials[blockIdx.x] = lds[0];
}

__global__ void scan_top_kernel(int* __restrict__ partials) {
    __shared__ int lds[256];
    int t = threadIdx.x;
    int v = (t < SCAN_NB) ? partials[t] : 0;
    lds[t] = v;
    __syncthreads();
    int incl = v;
    for (int off = 1; off < 256; off <<= 1) {
        int tmp = (t >= off) ? lds[t - off] : 0;
        __syncthreads();
        incl += tmp;
        lds[t] = incl;
        __syncthreads();
    }
    if (t < SCAN_NB) partials[t] = incl - v;  // exclusive
}

// writes offsets only (no node-level cursor needed anymore)
__global__ void scan_apply_kernel(const int* __restrict__ deg_i,
                                  const int* __restrict__ partials,
                                  int* __restrict__ offsets) {
    __shared__ int lds[256];
    int b = blockIdx.x, t = threadIdx.x;
    int base = b * SCAN_CHUNK + t * 4;
    int v[4];
    int s = 0;
    #pragma unroll
    for (int k = 0; k < 4; ++k) {
        int idx = base + k;
        v[k] = (idx < N_NODES) ? deg_i[idx] : 0;
        s += v[k];
    }
    lds[t] = s;
    __syncthreads();
    int incl = s;
    for (int off = 1; off < 256; off <<= 1) {
        int tmp = (t >= off) ? lds[t - off] : 0;
        __syncthreads();
        incl += tmp;
        lds[t] = incl;
        __syncthreads();
    }
    int run = incl - s + partials[b];
    #pragma unroll
    for (int k = 0; k < 4; ++k) {
        int idx = base + k;
        if (idx < N_NODES) {
            offsets[idx] = run;
            run += v[k];
        }
    }
}

// coarse_cursor[b] = coarse_off[b] = offsets[256*b]; coarse_off[BUCKETS] = E
__global__ void coarse_init_kernel(const int* __restrict__ offsets,
                                   int* __restrict__ coarse_cursor,
                                   int* __restrict__ coarse_off) {
    int t = blockIdx.x * blockDim.x + threadIdx.x;
    if (t < BUCKETS) {
        int v = offsets[t << 8];
        coarse_cursor[t] = v;
        coarse_off[t] = v;
    }
    if (t == BUCKETS) coarse_off[t] = E_EDGES;
}

// Pass A: bin edges into coarse buckets as packed (src | local_dst<<17).
// Per-WG LDS histogram -> one reserve atomic per bucket -> contiguous runs.
__global__ void binA_kernel(const int* __restrict__ src,
                            const int* __restrict__ dst,
                            int* __restrict__ coarse_cursor,
                            unsigned int* __restrict__ pairs) {
    __shared__ int lh[BUCKETS];
    int t = threadIdx.x;
    for (int i = t; i < BUCKETS; i += 256) lh[i] = 0;
    __syncthreads();
    int e0 = blockIdx.x * CHUNK_A;
    int e1 = min(e0 + CHUNK_A, E_EDGES);
    for (int i = e0 + t; i < e1; i += 256)
        atomicAdd(&lh[dst[i] >> 8], 1);
    __syncthreads();
    for (int i = t; i < BUCKETS; i += 256) {
        int c = lh[i];
        lh[i] = (c > 0) ? atomicAdd(&coarse_cursor[i], c) : 0;
    }
    __syncthreads();
    for (int i = e0 + t; i < e1; i += 256) {
        int d = dst[i];
        int b = d >> 8;
        int pos = atomicAdd(&lh[b], 1);
        pairs[pos] = (unsigned int)src[i] | (((unsigned int)(d & 255)) << 17);
    }
}

// Pass B: one WG per bucket; LDS per-node cursors; writes stay in a ~32KB window.
__global__ void binB_kernel(const unsigned int* __restrict__ pairs,
                            const int* __restrict__ offsets,
                            const int* __restrict__ coarse_off,
                            int* __restrict__ csr_src) {
    __shared__ int lcur[256];
    int b = blockIdx.x;
    int t = threadIdx.x;
    int node0 = b << 8;
    if (node0 + t < N_NODES) lcur[t] = offsets[node0 + t];
    __syncthreads();
    int start = coarse_off[b];
    int end = coarse_off[b + 1];
    for (int i = start + t; i < end; i += 256) {
        unsigned int p = pairs[i];
        int s = (int)(p & 0x1FFFFu);
        int ld = (int)(p >> 17);
        int pos = atomicAdd(&lcur[ld], 1);
        csr_src[pos] = s;
    }
}

// ---------------- layer 1 ----------------

__global__ void gather1_kernel(const int* __restrict__ csr_src,
                               const int* __restrict__ offsets,
                               const int* __restrict__ deg_i,
                               const float* __restrict__ x,
                               float* __restrict__ agg1) {
    int tid = blockIdx.x * blockDim.x + threadIdx.x;
    int n = tid >> 4;
    int f = tid & 15;
    if (n >= N_NODES || f >= F_IN) return;
    int start = offsets[n];
    int end = start + deg_i[n];
    float a0 = 0.f, a1 = 0.f, a2 = 0.f, a3 = 0.f;
    int i = start;
    for (; i + 4 <= end; i += 4) {
        int s0 = csr_src[i], s1 = csr_src[i + 1], s2 = csr_src[i + 2], s3 = csr_src[i + 3];
        a0 += x[s0 * F_IN + f];
        a1 += x[s1 * F_IN + f];
        a2 += x[s2 * F_IN + f];
        a3 += x[s3 * F_IN + f];
    }
    for (; i < end; ++i) a0 += x[csr_src[i] * F_IN + f];
    agg1[n * F_IN + f] = a0 + a1 + a2 + a3;
}

__global__ void layer1_node_kernel(const float* __restrict__ x,
                                   const float* __restrict__ agg1,
                                   const int* __restrict__ deg_i,
                                   const float* __restrict__ W1l,
                                   const float* __restrict__ W1r,
                                   const float* __restrict__ b1,
                                   float* __restrict__ h) {
    int tid = blockIdx.x * blockDim.x + threadIdx.x;
    int n = tid >> 6;
    int j = tid & 63;
    if (n >= N_NODES) return;
    float invd = 1.0f / fmaxf((float)deg_i[n], 1.0f);
    float acc = b1[j];
    #pragma unroll
    for (int f = 0; f < F_IN; ++f) {
        float a = agg1[n * F_IN + f] * invd;
        float xv = x[n * F_IN + f];
        acc += a * W1l[f * F_H + j] + xv * W1r[f * F_H + j];
    }
    h[n * F_H + j] = fmaxf(acc, 0.0f);
}

__global__ void p2_kernel(const float* __restrict__ h,
                          const float* __restrict__ W2l,
                          float* __restrict__ p2) {
    int tid = blockIdx.x * blockDim.x + threadIdx.x;
    int n = tid >> 5;
    int j = tid & 31;
    if (n >= N_NODES) return;
    float acc = 0.0f;
    const float* hrow = h + n * F_H;
    #pragma unroll
    for (int k = 0; k < F_H; ++k) acc += hrow[k] * W2l[k * F_E + j];
    p2[n * F_E + j] = acc;
}

// ---------------- layer 2 fused ----------------

__global__ void layer2_fused_kernel(const int* __restrict__ csr_src,
                                    const int* __restrict__ offsets,
                                    const int* __restrict__ deg_i,
                                    const float* __restrict__ p2,
                                    const float* __restrict__ h,
                                    const float* __restrict__ W2r,
                                    const float* __restrict__ b2,
                                    const float* __restrict__ Wc,
                                    const float* __restrict__ bc,
                                    float* __restrict__ emb,
                                    float* __restrict__ logits) {
    int tid = blockIdx.x * blockDim.x + threadIdx.x;
    int n = tid >> 5;
    int j = tid & 31;
    if (n >= N_NODES) return;
    int start = offsets[n];
    int cnt = deg_i[n];
    int end = start + cnt;
    float a0 = 0.f, a1 = 0.f, a2 = 0.f, a3 = 0.f;
    int i = start;
    for (; i + 4 <= end; i += 4) {
        int s0 = csr_src[i], s1 = csr_src[i + 1], s2 = csr_src[i + 2], s3 = csr_src[i + 3];
        a0 += p2[s0 * F_E + j];
        a1 += p2[s1 * F_E + j];
        a2 += p2[s2 * F_E + j];
        a3 += p2[s3 * F_E + j];
    }
    for (; i < end; ++i) a0 += p2[csr_src[i] * F_E + j];
    float invd = 1.0f / fmaxf((float)cnt, 1.0f);
    float acc = (a0 + a1 + a2 + a3) * invd + b2[j];
    const float* hrow = h + n * F_H;
    #pragma unroll
    for (int k = 0; k < F_H; ++k) acc += hrow[k] * W2r[k * F_E + j];
    float e = fmaxf(acc, 0.0f);
    emb[n * F_E + j] = e;
    float c0 = e * Wc[j * 3 + 0];
    float c1 = e * Wc[j * 3 + 1];
    float c2 = e * Wc[j * 3 + 2];
    #pragma unroll
    for (int m = 1; m < 32; m <<= 1) {
        c0 += __shfl_xor(c0, m);
        c1 += __shfl_xor(c1, m);
        c2 += __shfl_xor(c2, m);
    }
    if (j == 0) {
        logits[n * 3 + 0] = c0 + bc[0];
        logits[n * 3 + 1] = c1 + bc[1];
        logits[n * 3 + 2] = c2 + bc[2];
    }
}

extern "C" void kernel_launch(void* const* d_in, const int* in_sizes, int n_in,
                              void* d_out, int out_size, void* d_ws, size_t ws_size,
                              hipStream_t stream) {
    const float* x   = (const float*)d_in[0];
    const int*   ei  = (const int*)d_in[1];
    const float* W1l = (const float*)d_in[2];
    const float* W1r = (const float*)d_in[3];
    const float* b1  = (const float*)d_in[4];
    const float* W2l = (const float*)d_in[5];
    const float* W2r = (const float*)d_in[6];
    const float* b2  = (const float*)d_in[7];
    const float* Wc  = (const float*)d_in[8];
    const float* bc  = (const float*)d_in[9];

    const int* src = ei;
    const int* dst = ei + E_EDGES;

    float* out    = (float*)d_out;
    float* logits = out;
    float* emb    = out + (size_t)N_NODES * 3;

    // ws layout (4B units):
    //   deg_i         : N
    //   offsets       : N+1
    //   coarse_cursor : BUCKETS
    //   coarse_off    : BUCKETS+1
    //   partials      : 256
    //   csr_src       : E
    //   h             : 64N floats   (pairs[E] aliases this region — dead before h written)
    //   agg1/p2       : 32N floats
    int* ws_i          = (int*)d_ws;
    int* deg_i         = ws_i;
    int* offsets       = ws_i + N_NODES;
    int* coarse_cursor = ws_i + 2 * N_NODES + 1;
    int* coarse_off    = coarse_cursor + BUCKETS;
    int* partials      = coarse_off + BUCKETS + 1;
    int* csr_src       = partials + 256;
    float* h           = (float*)(csr_src + E_EDGES);
    unsigned int* pairs = (unsigned int*)h;          // alias: dead before h written
    float* p2region    = h + (size_t)F_H * N_NODES;  // 32N
    float* agg1        = p2region;
    float* p2          = p2region;

    hipMemsetAsync(deg_i, 0, (size_t)N_NODES * sizeof(int), stream);

    const int BS = 256;
    int eblocks = (E_EDGES + BS - 1) / BS;

    hist_kernel<<<eblocks, BS, 0, stream>>>(dst, deg_i);
    scan_partial_kernel<<<SCAN_NB, BS, 0, stream>>>(deg_i, partials);
    scan_top_kernel<<<1, 256, 0, stream>>>(partials);
    scan_apply_kernel<<<SCAN_NB, BS, 0, stream>>>(deg_i, partials, offsets);
    coarse_init_kernel<<<1, 512, 0, stream>>>(offsets, coarse_cursor, coarse_off);
    binA_kernel<<<NWG_A, BS, 0, stream>>>(src, dst, coarse_cursor, pairs);
    binB_kernel<<<BUCKETS, BS, 0, stream>>>(pairs, offsets, coarse_off, csr_src);

    gather1_kernel<<<(N_NODES * 16 + BS - 1) / BS, BS, 0, stream>>>(csr_src, offsets, deg_i, x, agg1);
    layer1_node_kernel<<<(N_NODES * 64 + BS - 1) / BS, BS, 0, stream>>>(x, agg1, deg_i, W1l, W1r, b1, h);
    p2_kernel<<<(N_NODES * 32 + BS - 1) / BS, BS, 0, stream>>>(h, W2l, p2);
    layer2_fused_kernel<<<(N_NODES * 32 + BS - 1) / BS, BS, 0, stream>>>(
        csr_src, offsets, deg_i, p2, h, W2r, b2, Wc, bc, emb, logits);
}

// Round 4
// 426.177 us; speedup vs baseline: 2.2828x; 1.2751x over previous
//
#include <hip/hip_runtime.h>

#define N_NODES 100000
#define E_EDGES 3200000
#define F_IN 11
#define F_H 64
#define F_E 32

#define BUCKETS ((N_NODES + 255) >> 8)   // 391 coarse buckets (dst>>8)
#define CHUNK_A 4096
#define NWG_A ((E_EDGES + CHUNK_A - 1) / CHUNK_A)  // 782

// ---------------- CSR construction (atomic-free at node granularity) ----------------

// per-WG LDS histogram of coarse buckets, flushed with <=BUCKETS global atomics/WG
__global__ void coarse_hist_kernel(const int* __restrict__ dst,
                                   int* __restrict__ coarse_count) {
    __shared__ int lh[BUCKETS];
    int t = threadIdx.x;
    for (int i = t; i < BUCKETS; i += 256) lh[i] = 0;
    __syncthreads();
    int e0 = blockIdx.x * CHUNK_A;
    int e1 = min(e0 + CHUNK_A, E_EDGES);
    for (int i = e0 + t; i < e1; i += 256)
        atomicAdd(&lh[dst[i] >> 8], 1);
    __syncthreads();
    for (int i = t; i < BUCKETS; i += 256) {
        int c = lh[i];
        if (c > 0) atomicAdd(&coarse_count[i], c);
    }
}

// single WG: exclusive scan of 391 bucket counts -> coarse_off, coarse_cursor
__global__ void scan_coarse_kernel(const int* __restrict__ coarse_count,
                                   int* __restrict__ coarse_off,
                                   int* __restrict__ coarse_cursor) {
    __shared__ int lds[512];
    int t = threadIdx.x;
    int v = (t < BUCKETS) ? coarse_count[t] : 0;
    lds[t] = v;
    __syncthreads();
    int incl = v;
    for (int off = 1; off < 512; off <<= 1) {
        int tmp = (t >= off) ? lds[t - off] : 0;
        __syncthreads();
        incl += tmp;
        lds[t] = incl;
        __syncthreads();
    }
    if (t <= BUCKETS) {
        int ex = incl - v;  // exclusive prefix
        coarse_off[t] = ex;
        if (t < BUCKETS) coarse_cursor[t] = ex;
    }
}

// Pass A: bin edges into coarse buckets as packed (src | local_dst<<17).
__global__ void binA_kernel(const int* __restrict__ src,
                            const int* __restrict__ dst,
                            int* __restrict__ coarse_cursor,
                            unsigned int* __restrict__ pairs) {
    __shared__ int lh[BUCKETS];
    int t = threadIdx.x;
    for (int i = t; i < BUCKETS; i += 256) lh[i] = 0;
    __syncthreads();
    int e0 = blockIdx.x * CHUNK_A;
    int e1 = min(e0 + CHUNK_A, E_EDGES);
    for (int i = e0 + t; i < e1; i += 256)
        atomicAdd(&lh[dst[i] >> 8], 1);
    __syncthreads();
    for (int i = t; i < BUCKETS; i += 256) {
        int c = lh[i];
        lh[i] = (c > 0) ? atomicAdd(&coarse_cursor[i], c) : 0;
    }
    __syncthreads();
    for (int i = e0 + t; i < e1; i += 256) {
        int d = dst[i];
        int b = d >> 8;
        int pos = atomicAdd(&lh[b], 1);
        pairs[pos] = (unsigned int)src[i] | (((unsigned int)(d & 255)) << 17);
    }
}

// Pass B: one WG per bucket. Derives per-node degree + offsets from pairs
// (LDS hist + LDS scan, coalesced global writes), then LDS-cursor scatter.
__global__ void binB_kernel(const unsigned int* __restrict__ pairs,
                            const int* __restrict__ coarse_off,
                            int* __restrict__ deg_i,
                            int* __restrict__ offsets,
                            int* __restrict__ csr_src) {
    __shared__ int lhist[256];
    __shared__ int lscan[256];
    __shared__ int lcur[256];
    int b = blockIdx.x;
    int t = threadIdx.x;
    lhist[t] = 0;
    __syncthreads();
    int start = coarse_off[b];
    int end = coarse_off[b + 1];
    // pass 1: local histogram
    for (int i = start + t; i < end; i += 256)
        atomicAdd(&lhist[pairs[i] >> 17], 1);
    __syncthreads();
    int cnt = lhist[t];
    // inclusive scan over 256
    lscan[t] = cnt;
    __syncthreads();
    int incl = cnt;
    for (int off = 1; off < 256; off <<= 1) {
        int tmp = (t >= off) ? lscan[t - off] : 0;
        __syncthreads();
        incl += tmp;
        lscan[t] = incl;
        __syncthreads();
    }
    int ex = start + incl - cnt;  // global exclusive offset for node (b<<8)+t
    int node = (b << 8) + t;
    if (node < N_NODES) {
        deg_i[node] = cnt;
        offsets[node] = ex;
    }
    lcur[t] = ex;
    __syncthreads();
    // pass 2: scatter (reads hit L2 — same WG just streamed them)
    for (int i = start + t; i < end; i += 256) {
        unsigned int p = pairs[i];
        int pos = atomicAdd(&lcur[p >> 17], 1);
        csr_src[pos] = (int)(p & 0x1FFFFu);
    }
}

// ---------------- layer 1 ----------------

__global__ void gather1_kernel(const int* __restrict__ csr_src,
                               const int* __restrict__ offsets,
                               const int* __restrict__ deg_i,
                               const float* __restrict__ x,
                               float* __restrict__ agg1) {
    int tid = blockIdx.x * blockDim.x + threadIdx.x;
    int n = tid >> 4;
    int f = tid & 15;
    if (n >= N_NODES || f >= F_IN) return;
    int start = offsets[n];
    int end = start + deg_i[n];
    float a0 = 0.f, a1 = 0.f, a2 = 0.f, a3 = 0.f;
    int i = start;
    for (; i + 4 <= end; i += 4) {
        int s0 = csr_src[i], s1 = csr_src[i + 1], s2 = csr_src[i + 2], s3 = csr_src[i + 3];
        a0 += x[s0 * F_IN + f];
        a1 += x[s1 * F_IN + f];
        a2 += x[s2 * F_IN + f];
        a3 += x[s3 * F_IN + f];
    }
    for (; i < end; ++i) a0 += x[csr_src[i] * F_IN + f];
    agg1[n * F_IN + f] = a0 + a1 + a2 + a3;
}

__global__ void layer1_node_kernel(const float* __restrict__ x,
                                   const float* __restrict__ agg1,
                                   const int* __restrict__ deg_i,
                                   const float* __restrict__ W1l,
                                   const float* __restrict__ W1r,
                                   const float* __restrict__ b1,
                                   float* __restrict__ h) {
    int tid = blockIdx.x * blockDim.x + threadIdx.x;
    int n = tid >> 6;
    int j = tid & 63;
    if (n >= N_NODES) return;
    float invd = 1.0f / fmaxf((float)deg_i[n], 1.0f);
    float acc = b1[j];
    #pragma unroll
    for (int f = 0; f < F_IN; ++f) {
        float a = agg1[n * F_IN + f] * invd;
        float xv = x[n * F_IN + f];
        acc += a * W1l[f * F_H + j] + xv * W1r[f * F_H + j];
    }
    h[n * F_H + j] = fmaxf(acc, 0.0f);
}

__global__ void p2_kernel(const float* __restrict__ h,
                          const float* __restrict__ W2l,
                          float* __restrict__ p2) {
    int tid = blockIdx.x * blockDim.x + threadIdx.x;
    int n = tid >> 5;
    int j = tid & 31;
    if (n >= N_NODES) return;
    float acc = 0.0f;
    const float* hrow = h + n * F_H;
    #pragma unroll
    for (int k = 0; k < F_H; ++k) acc += hrow[k] * W2l[k * F_E + j];
    p2[n * F_E + j] = acc;
}

// ---------------- layer 2 fused ----------------

__global__ void layer2_fused_kernel(const int* __restrict__ csr_src,
                                    const int* __restrict__ offsets,
                                    const int* __restrict__ deg_i,
                                    const float* __restrict__ p2,
                                    const float* __restrict__ h,
                                    const float* __restrict__ W2r,
                                    const float* __restrict__ b2,
                                    const float* __restrict__ Wc,
                                    const float* __restrict__ bc,
                                    float* __restrict__ emb,
                                    float* __restrict__ logits) {
    int tid = blockIdx.x * blockDim.x + threadIdx.x;
    int n = tid >> 5;
    int j = tid & 31;
    if (n >= N_NODES) return;
    int start = offsets[n];
    int cnt = deg_i[n];
    int end = start + cnt;
    float a0 = 0.f, a1 = 0.f, a2 = 0.f, a3 = 0.f;
    int i = start;
    for (; i + 4 <= end; i += 4) {
        int s0 = csr_src[i], s1 = csr_src[i + 1], s2 = csr_src[i + 2], s3 = csr_src[i + 3];
        a0 += p2[s0 * F_E + j];
        a1 += p2[s1 * F_E + j];
        a2 += p2[s2 * F_E + j];
        a3 += p2[s3 * F_E + j];
    }
    for (; i < end; ++i) a0 += p2[csr_src[i] * F_E + j];
    float invd = 1.0f / fmaxf((float)cnt, 1.0f);
    float acc = (a0 + a1 + a2 + a3) * invd + b2[j];
    const float* hrow = h + n * F_H;
    #pragma unroll
    for (int k = 0; k < F_H; ++k) acc += hrow[k] * W2r[k * F_E + j];
    float e = fmaxf(acc, 0.0f);
    emb[n * F_E + j] = e;
    float c0 = e * Wc[j * 3 + 0];
    float c1 = e * Wc[j * 3 + 1];
    float c2 = e * Wc[j * 3 + 2];
    #pragma unroll
    for (int m = 1; m < 32; m <<= 1) {
        c0 += __shfl_xor(c0, m);
        c1 += __shfl_xor(c1, m);
        c2 += __shfl_xor(c2, m);
    }
    if (j == 0) {
        logits[n * 3 + 0] = c0 + bc[0];
        logits[n * 3 + 1] = c1 + bc[1];
        logits[n * 3 + 2] = c2 + bc[2];
    }
}

extern "C" void kernel_launch(void* const* d_in, const int* in_sizes, int n_in,
                              void* d_out, int out_size, void* d_ws, size_t ws_size,
                              hipStream_t stream) {
    const float* x   = (const float*)d_in[0];
    const int*   ei  = (const int*)d_in[1];
    const float* W1l = (const float*)d_in[2];
    const float* W1r = (const float*)d_in[3];
    const float* b1  = (const float*)d_in[4];
    const float* W2l = (const float*)d_in[5];
    const float* W2r = (const float*)d_in[6];
    const float* b2  = (const float*)d_in[7];
    const float* Wc  = (const float*)d_in[8];
    const float* bc  = (const float*)d_in[9];

    const int* src = ei;
    const int* dst = ei + E_EDGES;

    float* out    = (float*)d_out;
    float* logits = out;
    float* emb    = out + (size_t)N_NODES * 3;

    // ws layout (4B units):
    //   deg_i         : N
    //   offsets       : N
    //   coarse_count  : BUCKETS
    //   coarse_off    : BUCKETS+1
    //   coarse_cursor : BUCKETS
    //   csr_src       : E
    //   h             : 64N floats   (pairs[E] aliases this region — dead before h written)
    //   agg1/p2       : 32N floats
    int* ws_i          = (int*)d_ws;
    int* deg_i         = ws_i;
    int* offsets       = ws_i + N_NODES;
    int* coarse_count  = ws_i + 2 * N_NODES;
    int* coarse_off    = coarse_count + BUCKETS;
    int* coarse_cursor = coarse_off + BUCKETS + 1;
    int* csr_src       = coarse_cursor + BUCKETS;
    float* h           = (float*)(csr_src + E_EDGES);
    unsigned int* pairs = (unsigned int*)h;          // alias: dead before h written
    float* p2region    = h + (size_t)F_H * N_NODES;
    float* agg1        = p2region;
    float* p2          = p2region;

    // zero only the tiny coarse histogram
    hipMemsetAsync(coarse_count, 0, BUCKETS * sizeof(int), stream);

    const int BS = 256;

    coarse_hist_kernel<<<NWG_A, BS, 0, stream>>>(dst, coarse_count);
    scan_coarse_kernel<<<1, 512, 0, stream>>>(coarse_count, coarse_off, coarse_cursor);
    binA_kernel<<<NWG_A, BS, 0, stream>>>(src, dst, coarse_cursor, pairs);
    binB_kernel<<<BUCKETS, BS, 0, stream>>>(pairs, coarse_off, deg_i, offsets, csr_src);

    gather1_kernel<<<(N_NODES * 16 + BS - 1) / BS, BS, 0, stream>>>(csr_src, offsets, deg_i, x, agg1);
    layer1_node_kernel<<<(N_NODES * 64 + BS - 1) / BS, BS, 0, stream>>>(x, agg1, deg_i, W1l, W1r, b1, h);
    p2_kernel<<<(N_NODES * 32 + BS - 1) / BS, BS, 0, stream>>>(h, W2l, p2);
    layer2_fused_kernel<<<(N_NODES * 32 + BS - 1) / BS, BS, 0, stream>>>(
        csr_src, offsets, deg_i, p2, h, W2r, b2, Wc, bc, emb, logits);
}

// Round 5
// 407.616 us; speedup vs baseline: 2.3868x; 1.0455x over previous
//
#include <hip/hip_runtime.h>
#include <hip/hip_fp16.h>

#define N_NODES 100000
#define E_EDGES 3200000
#define F_IN 11
#define F_H 64
#define F_E 32

#define BUCKETS ((N_NODES + 255) >> 8)   // 391 coarse buckets (dst>>8)
#define CHUNK_A 4096
#define NWG_A ((E_EDGES + CHUNK_A - 1) / CHUNK_A)  // 782

// ---------------- CSR construction ----------------

__global__ void coarse_hist_kernel(const int* __restrict__ dst,
                                   int* __restrict__ coarse_count) {
    __shared__ int lh[BUCKETS];
    int t = threadIdx.x;
    for (int i = t; i < BUCKETS; i += 256) lh[i] = 0;
    __syncthreads();
    int e0 = blockIdx.x * CHUNK_A;
    int e1 = min(e0 + CHUNK_A, E_EDGES);
    for (int i = e0 + t; i < e1; i += 256)
        atomicAdd(&lh[dst[i] >> 8], 1);
    __syncthreads();
    for (int i = t; i < BUCKETS; i += 256) {
        int c = lh[i];
        if (c > 0) atomicAdd(&coarse_count[i], c);
    }
}

__global__ void scan_coarse_kernel(const int* __restrict__ coarse_count,
                                   int* __restrict__ coarse_off,
                                   int* __restrict__ coarse_cursor) {
    __shared__ int lds[512];
    int t = threadIdx.x;
    int v = (t < BUCKETS) ? coarse_count[t] : 0;
    lds[t] = v;
    __syncthreads();
    int incl = v;
    for (int off = 1; off < 512; off <<= 1) {
        int tmp = (t >= off) ? lds[t - off] : 0;
        __syncthreads();
        incl += tmp;
        lds[t] = incl;
        __syncthreads();
    }
    if (t <= BUCKETS) {
        int ex = incl - v;
        coarse_off[t] = ex;
        if (t < BUCKETS) coarse_cursor[t] = ex;
    }
}

__global__ void binA_kernel(const int* __restrict__ src,
                            const int* __restrict__ dst,
                            int* __restrict__ coarse_cursor,
                            unsigned int* __restrict__ pairs) {
    __shared__ int lh[BUCKETS];
    int t = threadIdx.x;
    for (int i = t; i < BUCKETS; i += 256) lh[i] = 0;
    __syncthreads();
    int e0 = blockIdx.x * CHUNK_A;
    int e1 = min(e0 + CHUNK_A, E_EDGES);
    for (int i = e0 + t; i < e1; i += 256)
        atomicAdd(&lh[dst[i] >> 8], 1);
    __syncthreads();
    for (int i = t; i < BUCKETS; i += 256) {
        int c = lh[i];
        lh[i] = (c > 0) ? atomicAdd(&coarse_cursor[i], c) : 0;
    }
    __syncthreads();
    for (int i = e0 + t; i < e1; i += 256) {
        int d = dst[i];
        int b = d >> 8;
        int pos = atomicAdd(&lh[b], 1);
        pairs[pos] = (unsigned int)src[i] | (((unsigned int)(d & 255)) << 17);
    }
}

__global__ void binB_kernel(const unsigned int* __restrict__ pairs,
                            const int* __restrict__ coarse_off,
                            int* __restrict__ deg_i,
                            int* __restrict__ offsets,
                            int* __restrict__ csr_src) {
    __shared__ int lhist[256];
    __shared__ int lscan[256];
    __shared__ int lcur[256];
    int b = blockIdx.x;
    int t = threadIdx.x;
    lhist[t] = 0;
    __syncthreads();
    int start = coarse_off[b];
    int end = coarse_off[b + 1];
    for (int i = start + t; i < end; i += 256)
        atomicAdd(&lhist[pairs[i] >> 17], 1);
    __syncthreads();
    int cnt = lhist[t];
    lscan[t] = cnt;
    __syncthreads();
    int incl = cnt;
    for (int off = 1; off < 256; off <<= 1) {
        int tmp = (t >= off) ? lscan[t - off] : 0;
        __syncthreads();
        incl += tmp;
        lscan[t] = incl;
        __syncthreads();
    }
    int ex = start + incl - cnt;
    int node = (b << 8) + t;
    if (node < N_NODES) {
        deg_i[node] = cnt;
        offsets[node] = ex;
    }
    lcur[t] = ex;
    __syncthreads();
    for (int i = start + t; i < end; i += 256) {
        unsigned int p = pairs[i];
        int pos = atomicAdd(&lcur[p >> 17], 1);
        csr_src[pos] = (int)(p & 0x1FFFFu);
    }
}

// ---------------- fp16 conversion of x ----------------
// xh[n][0..11], padded to 12 halves (24B rows); 2.4 MB — fits each XCD's 4 MiB L2.
__global__ void convert_x_kernel(const float* __restrict__ x, __half* __restrict__ xh) {
    int tid = blockIdx.x * blockDim.x + threadIdx.x;
    if (tid >= N_NODES * 12) return;
    int n = tid / 12;
    int f = tid - n * 12;
    xh[tid] = __float2half((f < F_IN) ? x[n * F_IN + f] : 0.0f);
}

// ---------------- layer 1 ----------------

__global__ void gather1_kernel(const int* __restrict__ csr_src,
                               const int* __restrict__ offsets,
                               const int* __restrict__ deg_i,
                               const __half* __restrict__ xh,
                               float* __restrict__ agg1) {
    int tid = blockIdx.x * blockDim.x + threadIdx.x;
    int n = tid >> 4;
    int f = tid & 15;
    if (n >= N_NODES || f >= F_IN) return;
    int start = offsets[n];
    int end = start + deg_i[n];
    float a0 = 0.f, a1 = 0.f, a2 = 0.f, a3 = 0.f;
    int i = start;
    for (; i + 4 <= end; i += 4) {
        int s0 = csr_src[i], s1 = csr_src[i + 1], s2 = csr_src[i + 2], s3 = csr_src[i + 3];
        a0 += __half2float(xh[s0 * 12 + f]);
        a1 += __half2float(xh[s1 * 12 + f]);
        a2 += __half2float(xh[s2 * 12 + f]);
        a3 += __half2float(xh[s3 * 12 + f]);
    }
    for (; i < end; ++i) a0 += __half2float(xh[csr_src[i] * 12 + f]);
    agg1[n * F_IN + f] = a0 + a1 + a2 + a3;
}

__global__ void layer1_node_kernel(const float* __restrict__ x,
                                   const float* __restrict__ agg1,
                                   const int* __restrict__ deg_i,
                                   const float* __restrict__ W1l,
                                   const float* __restrict__ W1r,
                                   const float* __restrict__ b1,
                                   float* __restrict__ h) {
    int tid = blockIdx.x * blockDim.x + threadIdx.x;
    int n = tid >> 6;
    int j = tid & 63;
    if (n >= N_NODES) return;
    float invd = 1.0f / fmaxf((float)deg_i[n], 1.0f);
    float acc = b1[j];
    #pragma unroll
    for (int f = 0; f < F_IN; ++f) {
        float a = agg1[n * F_IN + f] * invd;
        float xv = x[n * F_IN + f];
        acc += a * W1l[f * F_H + j] + xv * W1r[f * F_H + j];
    }
    h[n * F_H + j] = fmaxf(acc, 0.0f);
}

// p2h = fp16(h @ W2l), thread = (n, j<32)
__global__ void proj2_kernel(const float* __restrict__ h,
                             const float* __restrict__ W2l,
                             __half* __restrict__ p2h) {
    int tid = blockIdx.x * blockDim.x + threadIdx.x;
    int n = tid >> 5;
    int j = tid & 31;
    if (n >= N_NODES) return;
    float acc = 0.0f;
    const float* hrow = h + n * F_H;
    #pragma unroll
    for (int k = 0; k < F_H; ++k) acc += hrow[k] * W2l[k * F_E + j];
    p2h[n * F_E + j] = __float2half(acc);
}

// ---------------- layer 2 fused ----------------

__global__ void layer2_fused_kernel(const int* __restrict__ csr_src,
                                    const int* __restrict__ offsets,
                                    const int* __restrict__ deg_i,
                                    const __half* __restrict__ p2h,
                                    const float* __restrict__ h,
                                    const float* __restrict__ W2r,
                                    const float* __restrict__ b2,
                                    const float* __restrict__ Wc,
                                    const float* __restrict__ bc,
                                    float* __restrict__ emb,
                                    float* __restrict__ logits) {
    int tid = blockIdx.x * blockDim.x + threadIdx.x;
    int n = tid >> 5;
    int j = tid & 31;
    if (n >= N_NODES) return;
    int start = offsets[n];
    int cnt = deg_i[n];
    int end = start + cnt;
    float a0 = 0.f, a1 = 0.f, a2 = 0.f, a3 = 0.f;
    int i = start;
    for (; i + 8 <= end; i += 8) {
        int s0 = csr_src[i],     s1 = csr_src[i + 1], s2 = csr_src[i + 2], s3 = csr_src[i + 3];
        int s4 = csr_src[i + 4], s5 = csr_src[i + 5], s6 = csr_src[i + 6], s7 = csr_src[i + 7];
        float v0 = __half2float(p2h[s0 * F_E + j]);
        float v1 = __half2float(p2h[s1 * F_E + j]);
        float v2 = __half2float(p2h[s2 * F_E + j]);
        float v3 = __half2float(p2h[s3 * F_E + j]);
        float v4 = __half2float(p2h[s4 * F_E + j]);
        float v5 = __half2float(p2h[s5 * F_E + j]);
        float v6 = __half2float(p2h[s6 * F_E + j]);
        float v7 = __half2float(p2h[s7 * F_E + j]);
        a0 += v0 + v4;
        a1 += v1 + v5;
        a2 += v2 + v6;
        a3 += v3 + v7;
    }
    for (; i < end; ++i) a0 += __half2float(p2h[csr_src[i] * F_E + j]);
    float invd = 1.0f / fmaxf((float)cnt, 1.0f);
    float acc = (a0 + a1 + a2 + a3) * invd + b2[j];
    const float* hrow = h + n * F_H;
    #pragma unroll
    for (int k = 0; k < F_H; ++k) acc += hrow[k] * W2r[k * F_E + j];
    float e = fmaxf(acc, 0.0f);
    emb[n * F_E + j] = e;
    float c0 = e * Wc[j * 3 + 0];
    float c1 = e * Wc[j * 3 + 1];
    float c2 = e * Wc[j * 3 + 2];
    #pragma unroll
    for (int m = 1; m < 32; m <<= 1) {
        c0 += __shfl_xor(c0, m);
        c1 += __shfl_xor(c1, m);
        c2 += __shfl_xor(c2, m);
    }
    if (j == 0) {
        logits[n * 3 + 0] = c0 + bc[0];
        logits[n * 3 + 1] = c1 + bc[1];
        logits[n * 3 + 2] = c2 + bc[2];
    }
}

extern "C" void kernel_launch(void* const* d_in, const int* in_sizes, int n_in,
                              void* d_out, int out_size, void* d_ws, size_t ws_size,
                              hipStream_t stream) {
    const float* x   = (const float*)d_in[0];
    const int*   ei  = (const int*)d_in[1];
    const float* W1l = (const float*)d_in[2];
    const float* W1r = (const float*)d_in[3];
    const float* b1  = (const float*)d_in[4];
    const float* W2l = (const float*)d_in[5];
    const float* W2r = (const float*)d_in[6];
    const float* b2  = (const float*)d_in[7];
    const float* Wc  = (const float*)d_in[8];
    const float* bc  = (const float*)d_in[9];

    const int* src = ei;
    const int* dst = ei + E_EDGES;

    float* out    = (float*)d_out;
    float* logits = out;
    float* emb    = out + (size_t)N_NODES * 3;

    // ws layout (4B units):
    //   deg_i         : N
    //   offsets       : N
    //   coarse_count  : BUCKETS; coarse_off : BUCKETS+1; coarse_cursor : BUCKETS
    //   csr_src       : E
    //   h             : 64N floats   (pairs[E] aliases — dead before h written)
    //   scratch S     : 17N floats:
    //     phase 1: xh (6N units as halves) + agg1 (11N floats)
    //     phase 2: p2h (16N units as halves) — overwrites xh/agg1 after both dead
    int* ws_i          = (int*)d_ws;
    int* deg_i         = ws_i;
    int* offsets       = ws_i + N_NODES;
    int* coarse_count  = ws_i + 2 * N_NODES;
    int* coarse_off    = coarse_count + BUCKETS;
    int* coarse_cursor = coarse_off + BUCKETS + 1;
    int* csr_src       = coarse_cursor + BUCKETS;
    float* h           = (float*)(csr_src + E_EDGES);
    unsigned int* pairs = (unsigned int*)h;               // alias, dead before h written
    float* S           = h + (size_t)F_H * N_NODES;       // 17N floats scratch
    __half* xh         = (__half*)S;                      // 12N halves = 6N units
    float* agg1        = S + (size_t)6 * N_NODES;         // 11N floats
    __half* p2h        = (__half*)S;                      // 32N halves = 16N units (phase 2)

    hipMemsetAsync(coarse_count, 0, BUCKETS * sizeof(int), stream);

    const int BS = 256;

    coarse_hist_kernel<<<NWG_A, BS, 0, stream>>>(dst, coarse_count);
    scan_coarse_kernel<<<1, 512, 0, stream>>>(coarse_count, coarse_off, coarse_cursor);
    binA_kernel<<<NWG_A, BS, 0, stream>>>(src, dst, coarse_cursor, pairs);
    binB_kernel<<<BUCKETS, BS, 0, stream>>>(pairs, coarse_off, deg_i, offsets, csr_src);

    convert_x_kernel<<<(N_NODES * 12 + BS - 1) / BS, BS, 0, stream>>>(x, xh);
    gather1_kernel<<<(N_NODES * 16 + BS - 1) / BS, BS, 0, stream>>>(csr_src, offsets, deg_i, xh, agg1);
    layer1_node_kernel<<<(N_NODES * 64 + BS - 1) / BS, BS, 0, stream>>>(x, agg1, deg_i, W1l, W1r, b1, h);
    proj2_kernel<<<(N_NODES * 32 + BS - 1) / BS, BS, 0, stream>>>(h, W2l, p2h);
    layer2_fused_kernel<<<(N_NODES * 32 + BS - 1) / BS, BS, 0, stream>>>(
        csr_src, offsets, deg_i, p2h, h, W2r, b2, Wc, bc, emb, logits);
}

// Round 6
// 358.865 us; speedup vs baseline: 2.7110x; 1.1358x over previous
//
#include <hip/hip_runtime.h>
#include <hip/hip_fp16.h>

#define N_NODES 100000
#define E_EDGES 3200000
#define F_IN 11
#define F_H 64
#define F_E 32

#define BUCKETS ((N_NODES + 255) >> 8)   // 391 coarse buckets (dst>>8)
#define CAP 16352                        // slack bucket capacity (expected load ~8192, +90 sigma)
#define CHUNK_A 4096
#define NWG_A ((E_EDGES + CHUNK_A - 1) / CHUNK_A)  // 782

// ---------------- CSR construction (no counting pass; slack buckets) ----------------

// Pass A: bin edges into slack buckets as packed (src | local_dst<<17).
// Per-WG LDS histogram -> one reserve atomic per touched bucket -> contiguous runs.
__global__ void binA_kernel(const int* __restrict__ src,
                            const int* __restrict__ dst,
                            int* __restrict__ cursor,
                            unsigned int* __restrict__ pairs) {
    __shared__ int lh[BUCKETS];
    int t = threadIdx.x;
    for (int i = t; i < BUCKETS; i += 256) lh[i] = 0;
    __syncthreads();
    int e0 = blockIdx.x * CHUNK_A;
    int e1 = min(e0 + CHUNK_A, E_EDGES);
    for (int i = e0 + t; i < e1; i += 256)
        atomicAdd(&lh[dst[i] >> 8], 1);
    __syncthreads();
    for (int i = t; i < BUCKETS; i += 256) {
        int c = lh[i];
        lh[i] = (c > 0) ? (i * CAP + atomicAdd(&cursor[i], c)) : 0;
    }
    __syncthreads();
    for (int i = e0 + t; i < e1; i += 256) {
        int d = dst[i];
        int b = d >> 8;
        int pos = atomicAdd(&lh[b], 1);
        pairs[pos] = (unsigned int)src[i] | (((unsigned int)(d & 255)) << 17);
    }
}

// Pass B: one WG per bucket. Derives per-node degree + offsets (into the slack
// csr layout) via LDS hist + LDS scan, then LDS-cursor scatter.
__global__ void binB_kernel(const unsigned int* __restrict__ pairs,
                            const int* __restrict__ cursor,
                            int* __restrict__ deg_i,
                            int* __restrict__ offsets,
                            int* __restrict__ csr_src) {
    __shared__ int lhist[256];
    __shared__ int lscan[256];
    __shared__ int lcur[256];
    int b = blockIdx.x;
    int t = threadIdx.x;
    lhist[t] = 0;
    __syncthreads();
    int start = b * CAP;
    int end = start + cursor[b];
    for (int i = start + t; i < end; i += 256)
        atomicAdd(&lhist[pairs[i] >> 17], 1);
    __syncthreads();
    int cnt = lhist[t];
    lscan[t] = cnt;
    __syncthreads();
    int incl = cnt;
    for (int off = 1; off < 256; off <<= 1) {
        int tmp = (t >= off) ? lscan[t - off] : 0;
        __syncthreads();
        incl += tmp;
        lscan[t] = incl;
        __syncthreads();
    }
    int ex = start + incl - cnt;  // offset within slack csr layout
    int node = (b << 8) + t;
    if (node < N_NODES) {
        deg_i[node] = cnt;
        offsets[node] = ex;
    }
    lcur[t] = ex;
    __syncthreads();
    for (int i = start + t; i < end; i += 256) {
        unsigned int p = pairs[i];
        int pos = atomicAdd(&lcur[p >> 17], 1);
        csr_src[pos] = (int)(p & 0x1FFFFu);
    }
}

// ---------------- fp16 conversion of x ----------------
// xh[n][0..11] padded to 12 halves (24B rows); 2.4 MB.
__global__ void convert_x_kernel(const float* __restrict__ x, __half* __restrict__ xh) {
    int tid = blockIdx.x * blockDim.x + threadIdx.x;
    if (tid >= N_NODES * 12) return;
    int n = tid / 12;
    int f = tid - n * 12;
    xh[tid] = __float2half((f < F_IN) ? x[n * F_IN + f] : 0.0f);
}

// ---------------- layer 1 ----------------

// gather via half2: 8 lanes/node, lanes 0..5 active (6 half2 = 12 halves/row)
__global__ void gather1_kernel(const int* __restrict__ csr_src,
                               const int* __restrict__ offsets,
                               const int* __restrict__ deg_i,
                               const __half2* __restrict__ xh2,
                               float* __restrict__ agg1) {
    int tid = blockIdx.x * blockDim.x + threadIdx.x;
    int n = tid >> 3;
    int f2 = tid & 7;
    if (n >= N_NODES || f2 >= 6) return;
    int start = offsets[n];
    int end = start + deg_i[n];
    float2 a0 = {0.f, 0.f}, a1 = {0.f, 0.f}, a2 = {0.f, 0.f}, a3 = {0.f, 0.f};
    int i = start;
    for (; i + 4 <= end; i += 4) {
        int s0 = csr_src[i], s1 = csr_src[i + 1], s2 = csr_src[i + 2], s3 = csr_src[i + 3];
        float2 v0 = __half22float2(xh2[s0 * 6 + f2]);
        float2 v1 = __half22float2(xh2[s1 * 6 + f2]);
        float2 v2 = __half22float2(xh2[s2 * 6 + f2]);
        float2 v3 = __half22float2(xh2[s3 * 6 + f2]);
        a0.x += v0.x; a0.y += v0.y;
        a1.x += v1.x; a1.y += v1.y;
        a2.x += v2.x; a2.y += v2.y;
        a3.x += v3.x; a3.y += v3.y;
    }
    for (; i < end; ++i) {
        float2 v = __half22float2(xh2[csr_src[i] * 6 + f2]);
        a0.x += v.x; a0.y += v.y;
    }
    float2 r;
    r.x = a0.x + a1.x + a2.x + a3.x;
    r.y = a0.y + a1.y + a2.y + a3.y;
    ((float2*)agg1)[n * 6 + f2] = r;   // agg1 padded to 12 floats/node
}

// h = relu(agg1/deg * W1l + x * W1r + b1) stored as fp16; thread = (n, j<64)
__global__ void layer1_node_kernel(const float* __restrict__ x,
                                   const float* __restrict__ agg1,
                                   const int* __restrict__ deg_i,
                                   const float* __restrict__ W1l,
                                   const float* __restrict__ W1r,
                                   const float* __restrict__ b1,
                                   __half* __restrict__ hh) {
    int tid = blockIdx.x * blockDim.x + threadIdx.x;
    int n = tid >> 6;
    int j = tid & 63;
    if (n >= N_NODES) return;
    float invd = 1.0f / fmaxf((float)deg_i[n], 1.0f);
    float acc = b1[j];
    #pragma unroll
    for (int f = 0; f < F_IN; ++f) {
        float a = agg1[n * 12 + f] * invd;
        float xv = x[n * F_IN + f];
        acc += a * W1l[f * F_H + j] + xv * W1r[f * F_H + j];
    }
    hh[n * F_H + j] = __float2half(fmaxf(acc, 0.0f));
}

// p2h = fp16(h @ W2l), thread = (n, j<32), h read as half2
__global__ void proj2_kernel(const __half2* __restrict__ hh2,
                             const float* __restrict__ W2l,
                             __half* __restrict__ p2h) {
    int tid = blockIdx.x * blockDim.x + threadIdx.x;
    int n = tid >> 5;
    int j = tid & 31;
    if (n >= N_NODES) return;
    const __half2* hrow = hh2 + n * 32;
    float acc = 0.0f;
    #pragma unroll
    for (int k2 = 0; k2 < 32; ++k2) {
        float2 hv = __half22float2(hrow[k2]);
        acc += hv.x * W2l[(2 * k2) * F_E + j] + hv.y * W2l[(2 * k2 + 1) * F_E + j];
    }
    p2h[n * F_E + j] = __float2half(acc);
}

// ---------------- layer 2 fused: half2 gather + h@W2r + relu + logits ----------------
// 16 lanes per node; each lane owns features (2j, 2j+1).
__global__ void layer2_fused_kernel(const int* __restrict__ csr_src,
                                    const int* __restrict__ offsets,
                                    const int* __restrict__ deg_i,
                                    const __half2* __restrict__ p2h2,
                                    const __half2* __restrict__ hh2,
                                    const float* __restrict__ W2r,
                                    const float* __restrict__ b2,
                                    const float* __restrict__ Wc,
                                    const float* __restrict__ bc,
                                    float* __restrict__ emb,
                                    float* __restrict__ logits) {
    int tid = blockIdx.x * blockDim.x + threadIdx.x;
    int n = tid >> 4;
    int l = tid & 15;
    if (n >= N_NODES) return;
    int start = offsets[n];
    int cnt = deg_i[n];
    int end = start + cnt;
    float2 a0 = {0.f, 0.f}, a1 = {0.f, 0.f}, a2 = {0.f, 0.f}, a3 = {0.f, 0.f};
    int i = start;
    for (; i + 8 <= end; i += 8) {
        int s0 = csr_src[i],     s1 = csr_src[i + 1], s2 = csr_src[i + 2], s3 = csr_src[i + 3];
        int s4 = csr_src[i + 4], s5 = csr_src[i + 5], s6 = csr_src[i + 6], s7 = csr_src[i + 7];
        float2 v0 = __half22float2(p2h2[s0 * 16 + l]);
        float2 v1 = __half22float2(p2h2[s1 * 16 + l]);
        float2 v2 = __half22float2(p2h2[s2 * 16 + l]);
        float2 v3 = __half22float2(p2h2[s3 * 16 + l]);
        float2 v4 = __half22float2(p2h2[s4 * 16 + l]);
        float2 v5 = __half22float2(p2h2[s5 * 16 + l]);
        float2 v6 = __half22float2(p2h2[s6 * 16 + l]);
        float2 v7 = __half22float2(p2h2[s7 * 16 + l]);
        a0.x += v0.x + v4.x; a0.y += v0.y + v4.y;
        a1.x += v1.x + v5.x; a1.y += v1.y + v5.y;
        a2.x += v2.x + v6.x; a2.y += v2.y + v6.y;
        a3.x += v3.x + v7.x; a3.y += v3.y + v7.y;
    }
    for (; i < end; ++i) {
        float2 v = __half22float2(p2h2[csr_src[i] * 16 + l]);
        a0.x += v.x; a0.y += v.y;
    }
    float invd = 1.0f / fmaxf((float)cnt, 1.0f);
    float2 bb = ((const float2*)b2)[l];
    float2 acc;
    acc.x = (a0.x + a1.x + a2.x + a3.x) * invd + bb.x;
    acc.y = (a0.y + a1.y + a2.y + a3.y) * invd + bb.y;
    const __half2* hrow = hh2 + n * 32;
    #pragma unroll
    for (int k2 = 0; k2 < 32; ++k2) {
        float2 hv = __half22float2(hrow[k2]);
        float2 wa = ((const float2*)(W2r + (2 * k2) * F_E))[l];
        float2 wb = ((const float2*)(W2r + (2 * k2 + 1) * F_E))[l];
        acc.x += hv.x * wa.x + hv.y * wb.x;
        acc.y += hv.x * wa.y + hv.y * wb.y;
    }
    float2 e;
    e.x = fmaxf(acc.x, 0.0f);
    e.y = fmaxf(acc.y, 0.0f);
    ((float2*)emb)[n * 16 + l] = e;
    float c0 = e.x * Wc[(2 * l) * 3 + 0] + e.y * Wc[(2 * l + 1) * 3 + 0];
    float c1 = e.x * Wc[(2 * l) * 3 + 1] + e.y * Wc[(2 * l + 1) * 3 + 1];
    float c2 = e.x * Wc[(2 * l) * 3 + 2] + e.y * Wc[(2 * l + 1) * 3 + 2];
    #pragma unroll
    for (int m = 1; m < 16; m <<= 1) {
        c0 += __shfl_xor(c0, m);
        c1 += __shfl_xor(c1, m);
        c2 += __shfl_xor(c2, m);
    }
    if (l == 0) {
        logits[n * 3 + 0] = c0 + bc[0];
        logits[n * 3 + 1] = c1 + bc[1];
        logits[n * 3 + 2] = c2 + bc[2];
    }
}

extern "C" void kernel_launch(void* const* d_in, const int* in_sizes, int n_in,
                              void* d_out, int out_size, void* d_ws, size_t ws_size,
                              hipStream_t stream) {
    const float* x   = (const float*)d_in[0];
    const int*   ei  = (const int*)d_in[1];
    const float* W1l = (const float*)d_in[2];
    const float* W1r = (const float*)d_in[3];
    const float* b1  = (const float*)d_in[4];
    const float* W2l = (const float*)d_in[5];
    const float* W2r = (const float*)d_in[6];
    const float* b2  = (const float*)d_in[7];
    const float* Wc  = (const float*)d_in[8];
    const float* bc  = (const float*)d_in[9];

    const int* src = ei;
    const int* dst = ei + E_EDGES;

    float* out    = (float*)d_out;
    float* logits = out;
    float* emb    = out + (size_t)N_NODES * 3;

    // ws layout (4B units):
    //   deg_i    : N
    //   offsets  : N
    //   cursor   : BUCKETS
    //   csr_src  : BUCKETS*CAP (slack)
    //   region2  : 66N units:
    //     pairs (BUCKETS*CAP, live binA..binB) aliases the front; then
    //     hh (32N) | p2h (16N) | xh (6N) | agg1 (12N)
    int* ws_i     = (int*)d_ws;
    int* deg_i    = ws_i;
    int* offsets  = ws_i + N_NODES;
    int* cursor   = ws_i + 2 * N_NODES;
    int* csr_src  = cursor + BUCKETS;
    int* region2  = csr_src + (size_t)BUCKETS * CAP;
    unsigned int* pairs = (unsigned int*)region2;                 // alias
    __half* hh    = (__half*)region2;                             // 64N halves = 32N units
    __half* p2h   = (__half*)(region2 + (size_t)32 * N_NODES);    // 32N halves = 16N units
    __half* xh    = (__half*)(region2 + (size_t)48 * N_NODES);    // 12N halves = 6N units
    float* agg1   = (float*)(region2 + (size_t)54 * N_NODES);     // 12N floats

    hipMemsetAsync(cursor, 0, BUCKETS * sizeof(int), stream);

    const int BS = 256;

    binA_kernel<<<NWG_A, BS, 0, stream>>>(src, dst, cursor, pairs);
    binB_kernel<<<BUCKETS, BS, 0, stream>>>(pairs, cursor, deg_i, offsets, csr_src);

    convert_x_kernel<<<(N_NODES * 12 + BS - 1) / BS, BS, 0, stream>>>(x, xh);
    gather1_kernel<<<(N_NODES * 8 + BS - 1) / BS, BS, 0, stream>>>(
        csr_src, offsets, deg_i, (const __half2*)xh, agg1);
    layer1_node_kernel<<<(N_NODES * 64 + BS - 1) / BS, BS, 0, stream>>>(
        x, agg1, deg_i, W1l, W1r, b1, hh);
    proj2_kernel<<<(N_NODES * 32 + BS - 1) / BS, BS, 0, stream>>>(
        (const __half2*)hh, W2l, p2h);
    layer2_fused_kernel<<<(N_NODES * 16 + BS - 1) / BS, BS, 0, stream>>>(
        csr_src, offsets, deg_i, (const __half2*)p2h, (const __half2*)hh,
        W2r, b2, Wc, bc, emb, logits);
}